// Round 4
// baseline (397.001 us; speedup 1.0000x reference)
//
#include <hip/hip_runtime.h>

typedef unsigned short u16;
typedef unsigned int u32;
typedef __bf16 bf16x8 __attribute__((ext_vector_type(8)));
typedef float f32x4 __attribute__((ext_vector_type(4)));
typedef u16 u16x8 __attribute__((ext_vector_type(8)));

__device__ __forceinline__ u16 f2bf(float f) {
    union { float f; u32 i; } v; v.f = f;
    u32 x = v.i;
    u32 r = (x + 0x7fffu + ((x >> 16) & 1u)) >> 16;
    return (u16)r;
}
__device__ __forceinline__ float bf2f(u16 u) {
    union { u32 i; float f; } v; v.i = ((u32)u) << 16; return v.f;
}

// async global->LDS, 16B per lane. LDS dest must be lane-linear per wave.
__device__ __forceinline__ void gld16(const void* g, void* l) {
    __builtin_amdgcn_global_load_lds(
        (const __attribute__((address_space(1))) void*)g,
        (__attribute__((address_space(3))) void*)l, 16, 0, 0);
}

// -------- weight transpose+convert: 4 matrices [512][512] fp32 -> bf16^T ---
__global__ __launch_bounds__(256) void transpose4(
    const float* __restrict__ s0, const float* __restrict__ s1,
    const float* __restrict__ s2, const float* __restrict__ s3,
    u16* __restrict__ d0, u16* __restrict__ d1,
    u16* __restrict__ d2, u16* __restrict__ d3)
{
    int bx = blockIdx.x;
    int mat = bx >> 8;          // 0..3
    int tile = bx & 255;        // 16x16 tiles of 32x32
    int tx = (tile & 15) * 32;
    int ty = (tile >> 4) * 32;
    const float* src = (mat == 0) ? s0 : (mat == 1) ? s1 : (mat == 2) ? s2 : s3;
    u16* dst = (mat == 0) ? d0 : (mat == 1) ? d1 : (mat == 2) ? d2 : d3;

    __shared__ u16 tl[32][33];
    int col = threadIdx.x & 31;
    int r8  = threadIdx.x >> 5;   // 0..7
    #pragma unroll
    for (int k = 0; k < 4; ++k) {
        int rr = r8 + k * 8;
        tl[rr][col] = f2bf(src[(ty + rr) * 512 + tx + col]);
    }
    __syncthreads();
    #pragma unroll
    for (int k = 0; k < 4; ++k) {
        int rr = r8 + k * 8;
        dst[(tx + rr) * 512 + ty + col] = tl[col][rr];
    }
}

// -------- LayerNorm over H=512: fp32 in -> bf16 out, one wave per row -----
__global__ __launch_bounds__(256) void ln_k(
    const float* __restrict__ x, const float* __restrict__ g,
    const float* __restrict__ b, u16* __restrict__ y, int rows)
{
    int gid = blockIdx.x * blockDim.x + threadIdx.x;
    int row = gid >> 6;
    int lane = gid & 63;
    if (row >= rows) return;

    const float* xr = x + (size_t)row * 512 + lane * 8;
    float4 a0 = *(const float4*)xr;
    float4 a1 = *(const float4*)(xr + 4);
    float f[8] = {a0.x, a0.y, a0.z, a0.w, a1.x, a1.y, a1.z, a1.w};
    float s = 0.f, s2 = 0.f;
    #pragma unroll
    for (int e = 0; e < 8; ++e) { s += f[e]; s2 += f[e] * f[e]; }
    #pragma unroll
    for (int o = 32; o > 0; o >>= 1) { s += __shfl_xor(s, o); s2 += __shfl_xor(s2, o); }
    const float inv = 1.0f / 512.0f;
    float mean = s * inv;
    float var  = s2 * inv - mean * mean;
    float rstd = rsqrtf(var + 1e-5f);

    float4 g0 = *(const float4*)(g + lane * 8);
    float4 g1 = *(const float4*)(g + lane * 8 + 4);
    float4 b0 = *(const float4*)(b + lane * 8);
    float4 b1 = *(const float4*)(b + lane * 8 + 4);
    float gg[8] = {g0.x, g0.y, g0.z, g0.w, g1.x, g1.y, g1.z, g1.w};
    float bb[8] = {b0.x, b0.y, b0.z, b0.w, b1.x, b1.y, b1.z, b1.w};
    u16x8 ov;
    #pragma unroll
    for (int e = 0; e < 8; ++e)
        ov[e] = f2bf((f[e] - mean) * rstd * gg[e] + bb[e]);
    *(u16x8*)(y + (size_t)row * 512 + lane * 8) = ov;
}

// -------- GEMM: C[M,N] = A[M,K](bf16) @ Bt[N,K](bf16)^T, 128x128 tile -----
// Staging via global_load_lds (width 16), granule-XOR on source + read side
// (rule 21; round-1 verified: FETCH ideal, LDS conflicts 0).
// EPILOGUE: acc-frags staged to LDS (unioned with staging bufs, post-loop),
// then contiguous 16B/lane stores -> full-line writes (fixes the ~2x HBM
// write amplification measured on the scalar-u16 epilogue).
// MODE 0: dual-B -> out0 = A@B0 + bias0 (bf16), out1 = A@B1 + bias1 (bf16)
// MODE 1: out0 = relu(A@B0 + bias0) (bf16)
// MODE 2: out0 = A@B0 + bias0 + resid (fp32 out; resid read coalesced,
//         same-offset same-thread -> alias-safe with out0)
template <int MODE>
__global__ __launch_bounds__(256, 2) void gemm_bt(
    const u16* __restrict__ A, const u16* __restrict__ Bt0,
    const u16* __restrict__ Bt1, const float* __restrict__ bias0,
    const float* __restrict__ bias1, const float* __restrict__ resid,
    void* __restrict__ out0v, u16* __restrict__ out1)
{
    constexpr int Kd = 512, Nd = 512;
    // MODE 0/1: 32 KiB (staging 24/16 KiB; C-stage u16 128x128 = 32 KiB)
    // MODE 2  : 64 KiB (C-stage f32 128x128)
    constexpr int SMEM_N = (MODE == 2) ? 32768 : 16384;
    __shared__ __align__(16) u16 smem[SMEM_N];
    u16* As  = smem;
    u16* Bs0 = smem + 4096;
    u16* Bs1 = smem + 8192;   // used only when MODE==0

    // XCD-contiguous tile remap (1024 % 8 == 0 -> bijective)
    int bx = blockIdx.x;
    bx = (bx & 7) * 128 + (bx >> 3);
    int m0 = (bx >> 2) * 128;
    int n0 = (bx & 3) * 128;
    int tid = threadIdx.x;
    int lane = tid & 63;
    int w = tid >> 6;
    int wm = w & 1, wn = w >> 1;
    int l16 = lane & 15;
    int quad = lane >> 4;

    f32x4 acc0[4][4] = {};
    f32x4 acc1[4][4] = {};

    // staging: chunk ch covers LDS granule ch (16B); it carries global
    // granule (ch&3) ^ ((row>>1)&3) of row = ch>>2.
    int ch0 = tid, ch1 = tid + 256;
    int row0 = ch0 >> 2, row1 = ch1 >> 2;
    int g0 = (ch0 & 3) ^ ((ch0 >> 3) & 3);
    int g1 = (ch1 & 3) ^ ((ch1 >> 3) & 3);
    const u16* a0p  = A   + (size_t)(m0 + row0) * Kd + g0 * 8;
    const u16* a1p  = A   + (size_t)(m0 + row1) * Kd + g1 * 8;
    const u16* b00p = Bt0 + (size_t)(n0 + row0) * Kd + g0 * 8;
    const u16* b01p = Bt0 + (size_t)(n0 + row1) * Kd + g1 * 8;
    const u16* b10p = (MODE == 0) ? Bt1 + (size_t)(n0 + row0) * Kd + g0 * 8 : nullptr;
    const u16* b11p = (MODE == 0) ? Bt1 + (size_t)(n0 + row1) * Kd + g1 * 8 : nullptr;

    for (int kt = 0; kt < Kd / 32; ++kt) {
        int k0 = kt * 32;
        gld16(a0p  + k0, &As [ch0 * 8]);
        gld16(a1p  + k0, &As [ch1 * 8]);
        gld16(b00p + k0, &Bs0[ch0 * 8]);
        gld16(b01p + k0, &Bs0[ch1 * 8]);
        if (MODE == 0) {
            gld16(b10p + k0, &Bs1[ch0 * 8]);
            gld16(b11p + k0, &Bs1[ch1 * 8]);
        }
        __syncthreads();

        bf16x8 af[4], bf0[4], bf1[4];
        #pragma unroll
        for (int i = 0; i < 4; ++i) {
            int ra = wm * 64 + i * 16 + l16;
            int rb = wn * 64 + i * 16 + l16;
            int ga = quad ^ ((ra >> 1) & 3);
            int gb = quad ^ ((rb >> 1) & 3);
            af[i]  = *(const bf16x8*)&As [ra * 32 + ga * 8];
            bf0[i] = *(const bf16x8*)&Bs0[rb * 32 + gb * 8];
            if (MODE == 0)
                bf1[i] = *(const bf16x8*)&Bs1[rb * 32 + gb * 8];
        }
        #pragma unroll
        for (int i = 0; i < 4; ++i)
            #pragma unroll
            for (int j = 0; j < 4; ++j) {
                acc0[i][j] = __builtin_amdgcn_mfma_f32_16x16x32_bf16(af[i], bf0[j], acc0[i][j], 0, 0, 0);
                if (MODE == 0)
                    acc1[i][j] = __builtin_amdgcn_mfma_f32_16x16x32_bf16(af[i], bf1[j], acc1[i][j], 0, 0, 0);
            }
        __syncthreads();
    }
    // (last loop-iteration sync drained all DMA -> smem reusable as C-stage)

    if (MODE != 2) {
        u16* Cs = smem;   // 128 x 128 u16
        // ---- pass 1: acc0 ----
        #pragma unroll
        for (int j = 0; j < 4; ++j) {
            float bv = bias0[n0 + wn * 64 + j * 16 + l16];
            #pragma unroll
            for (int i = 0; i < 4; ++i)
                #pragma unroll
                for (int r = 0; r < 4; ++r) {
                    float v = acc0[i][j][r] + bv;
                    if (MODE == 1) v = fmaxf(v, 0.f);
                    Cs[(wm * 64 + i * 16 + quad * 4 + r) * 128 + wn * 64 + j * 16 + l16] = f2bf(v);
                }
        }
        __syncthreads();
        #pragma unroll
        for (int k = 0; k < 8; ++k) {
            int c = tid + k * 256;
            int row = c >> 4, c8 = c & 15;
            *(u16x8*)((u16*)out0v + (size_t)(m0 + row) * Nd + n0 + c8 * 8) =
                *(const u16x8*)&Cs[row * 128 + c8 * 8];
        }
        if (MODE == 0) {
            __syncthreads();
            // ---- pass 2: acc1 ----
            #pragma unroll
            for (int j = 0; j < 4; ++j) {
                float bv = bias1[n0 + wn * 64 + j * 16 + l16];
                #pragma unroll
                for (int i = 0; i < 4; ++i)
                    #pragma unroll
                    for (int r = 0; r < 4; ++r)
                        Cs[(wm * 64 + i * 16 + quad * 4 + r) * 128 + wn * 64 + j * 16 + l16] =
                            f2bf(acc1[i][j][r] + bv);
            }
            __syncthreads();
            #pragma unroll
            for (int k = 0; k < 8; ++k) {
                int c = tid + k * 256;
                int row = c >> 4, c8 = c & 15;
                *(u16x8*)(out1 + (size_t)(m0 + row) * Nd + n0 + c8 * 8) =
                    *(const u16x8*)&Cs[row * 128 + c8 * 8];
            }
        }
    } else {
        float* Cf = (float*)smem;   // 128 x 128 f32
        #pragma unroll
        for (int j = 0; j < 4; ++j) {
            float bv = bias0[n0 + wn * 64 + j * 16 + l16];
            #pragma unroll
            for (int i = 0; i < 4; ++i)
                #pragma unroll
                for (int r = 0; r < 4; ++r)
                    Cf[(wm * 64 + i * 16 + quad * 4 + r) * 128 + wn * 64 + j * 16 + l16] =
                        acc0[i][j][r] + bv;
        }
        __syncthreads();
        #pragma unroll
        for (int k = 0; k < 16; ++k) {
            int c = tid + k * 256;
            int row = c >> 5, c4 = (c & 31) * 4;
            size_t off = (size_t)(m0 + row) * Nd + n0 + c4;
            float4 v = *(const float4*)&Cf[row * 128 + c4];
            const float4 rz = *(const float4*)(resid + off);
            v.x += rz.x; v.y += rz.y; v.z += rz.z; v.w += rz.w;
            *(float4*)((float*)out0v + off) = v;
        }
    }
}

// -------- minGRU scan (chunked linear recurrence) --------------------------
// h_t = c_t*h_{t-1} + v_t ; c = sigmoid(-k), v = sigmoid(k)*g(hp), h_0 = 0.5
// Chunk length 32 (256 chunks/seq). 3-level chunk-state scan.
__device__ __forceinline__ void gate_cv(u16 kraw, u16 hraw, float& c, float& v) {
    float kk = bf2f(kraw);
    float hh = bf2f(hraw);
    float z = 1.f / (1.f + __expf(-kk));   // sigmoid(k)
    c = 1.f / (1.f + __expf(kk));          // sigmoid(-k)
    float gg = (hh >= 0.f) ? (hh + 0.5f) : 1.f / (1.f + __expf(-hh));
    v = z * gg;
}

// Pass A: per-chunk (C, V) composition over chunk length 32.
__global__ __launch_bounds__(256) void scanA(
    const u16* __restrict__ kb, const u16* __restrict__ hp,
    float* __restrict__ chC, float* __restrict__ chV)
{
    int gid = blockIdx.x * 256 + threadIdx.x;   // 524288 threads
    int h = gid & 511;
    int rest = gid >> 9;
    int b = rest & 3;
    int ch = rest >> 2;             // 0..255
    size_t base = ((size_t)(b * 8192 + ch * 32)) * 512 + h;
    float C = 1.f, V = 0.f;
    #pragma unroll 8
    for (int t = 0; t < 32; ++t) {
        float c, v;
        gate_cv(kb[base + (size_t)t * 512], hp[base + (size_t)t * 512], c, v);
        C *= c;
        V = fmaf(c, V, v);
    }
    int s = b * 512 + h;
    chC[ch * 2048 + s] = C;
    chV[ch * 2048 + s] = V;
}

// Pass B1: compose 16 chunks -> superchunk state (16 superchunks/seq).
__global__ __launch_bounds__(256) void scanB1(
    const float* __restrict__ chC, const float* __restrict__ chV,
    float* __restrict__ scC, float* __restrict__ scV)
{
    int gid = blockIdx.x * 256 + threadIdx.x;  // 32768 threads
    int s = gid & 2047;
    int sc = gid >> 11;    // 0..15
    float C = 1.f, V = 0.f;
    #pragma unroll 4
    for (int i = 0; i < 16; ++i) {
        int ch = sc * 16 + i;
        float c = chC[ch * 2048 + s];
        float v = chV[ch * 2048 + s];
        C *= c;
        V = fmaf(c, V, v);
    }
    scC[sc * 2048 + s] = C;
    scV[sc * 2048 + s] = V;
}

// Pass B2: serial scan over 16 superchunk states; write start h per sc.
__global__ __launch_bounds__(256) void scanB2(
    const float* __restrict__ scC, const float* __restrict__ scV,
    float* __restrict__ sst)
{
    int s = blockIdx.x * 256 + threadIdx.x;   // 0..2047
    float hcur = 0.5f;
    #pragma unroll
    for (int sc = 0; sc < 16; ++sc) {
        sst[sc * 2048 + s] = hcur;
        hcur = fmaf(scC[sc * 2048 + s], hcur, scV[sc * 2048 + s]);
    }
}

// Pass B3: replay 16 chunks inside each superchunk; write start h per chunk.
__global__ __launch_bounds__(256) void scanB3(
    const float* __restrict__ chC, const float* __restrict__ chV,
    const float* __restrict__ sst, float* __restrict__ hst)
{
    int gid = blockIdx.x * 256 + threadIdx.x;  // 32768 threads
    int s = gid & 2047;
    int sc = gid >> 11;
    float hcur = sst[sc * 2048 + s];
    #pragma unroll 4
    for (int i = 0; i < 16; ++i) {
        int ch = sc * 16 + i;
        hst[ch * 2048 + s] = hcur;
        hcur = fmaf(chC[ch * 2048 + s], hcur, chV[ch * 2048 + s]);
    }
}

// Pass C + fused LN2: one 512-thread block per (b, chunk): 32 rows x 512 h.
// Replays the chunk (x2 = x + h), then LayerNorms each of the 32 rows
// (shfl wave-reduce + LDS partials) and writes bf16 LN2 output.
// a2 (LN2 out) goes IN-PLACE into kb: thread h reads kb[off]/hp[off] in
// loop 1 and writes a2 at the IDENTICAL offsets in loop 3 -> same-thread,
// per-thread-disjoint, race-free. This frees the old 'a' region for the
// FFN hidden buffer.
__global__ __launch_bounds__(512) void scanC_ln(
    const u16* __restrict__ kb, const u16* __restrict__ hp,
    const float* __restrict__ hst, const float* __restrict__ x,
    const float* __restrict__ g, const float* __restrict__ bia,
    float* __restrict__ x2, u16* __restrict__ aout)
{
    int h = threadIdx.x;            // 0..511
    int bx = blockIdx.x;            // 0..1023
    int b = bx >> 8;
    int ch = bx & 255;
    size_t base = ((size_t)(b * 8192 + ch * 32)) * 512 + h;
    float hcur = hst[ch * 2048 + b * 512 + h];

    float xv[32];
    #pragma unroll
    for (int t = 0; t < 32; ++t) {
        float c, v;
        size_t off = base + (size_t)t * 512;
        gate_cv(kb[off], hp[off], c, v);
        hcur = fmaf(c, hcur, v);
        xv[t] = x[off] + hcur;
    }

    __shared__ float sP[32][8], s2P[32][8];
    int lane = h & 63, w = h >> 6;
    #pragma unroll
    for (int t = 0; t < 32; ++t) {
        float s = xv[t], s2 = xv[t] * xv[t];
        #pragma unroll
        for (int o = 32; o > 0; o >>= 1) { s += __shfl_xor(s, o); s2 += __shfl_xor(s2, o); }
        if (lane == 0) { sP[t][w] = s; s2P[t][w] = s2; }
    }
    __syncthreads();

    float gg = g[h], bb = bia[h];
    const float inv = 1.0f / 512.0f;
    #pragma unroll
    for (int t = 0; t < 32; ++t) {
        float s = 0.f, s2 = 0.f;
        #pragma unroll
        for (int k = 0; k < 8; ++k) { s += sP[t][k]; s2 += s2P[t][k]; }
        float mean = s * inv;
        float var  = s2 * inv - mean * mean;
        float rstd = rsqrtf(var + 1e-5f);
        size_t off = base + (size_t)t * 512;
        x2[off] = xv[t];
        aout[off] = f2bf((xv[t] - mean) * rstd * gg + bb);
    }
}

// ---------------------------------------------------------------------------
// All I/O fp32 (per reference). Internals bf16 for MFMA.
// ws layout (footprint unchanged):
//   wt  @ 0      : 2 MiB   (4 transposed bf16 weights)
//   a   @ 3.5 MiB: 32 MiB  bf16. Lifetimes: LN1-out (read by gemm0) ->
//     scan temps alias it (chC/chV/hst/sc*) -> FFN hidden (gemm1 out).
//   kb  @ 35.5 M : 32 MiB  bf16. k-preact -> (in-place) LN2-out.
//   hp  @ 67.5 M : 32 MiB  bf16  h~ preact.
// d_out (fp32, 64 MiB) holds x2 after scanC_ln, then the final output.
extern "C" void kernel_launch(void* const* d_in, const int* in_sizes, int n_in,
                              void* d_out, int out_size, void* d_ws, size_t ws_size,
                              hipStream_t stream)
{
    const float* x    = (const float*)d_in[0];
    const float* ln1g = (const float*)d_in[1];
    const float* ln1b = (const float*)d_in[2];
    const float* Wz   = (const float*)d_in[3];
    const float* bz   = (const float*)d_in[4];
    const float* Wh   = (const float*)d_in[5];
    const float* bh   = (const float*)d_in[6];
    const float* ln2g = (const float*)d_in[7];
    const float* ln2b = (const float*)d_in[8];
    const float* W1   = (const float*)d_in[9];
    const float* b1   = (const float*)d_in[10];
    const float* W2   = (const float*)d_in[11];
    const float* b2   = (const float*)d_in[12];
    float* out = (float*)d_out;

    char* ws = (char*)d_ws;
    constexpr size_t MB = 1024 * 1024;
    u16* Wzt = (u16*)(ws);
    u16* Wht = Wzt + 262144;
    u16* W1t = Wzt + 524288;
    u16* W2t = Wzt + 786432;
    u16* a  = (u16*)(ws + 3 * MB + 512 * 1024);   // LN1 out / later FFN hidden
    u16* kb = (u16*)(ws + 35 * MB + 512 * 1024);  // k preact / later LN2 out
    u16* hp = (u16*)(ws + 67 * MB + 512 * 1024);
    // scan temps alias 'a' (dead in that interval)
    float* chC = (float*)(ws + 3 * MB + 512 * 1024);
    float* chV = chC + 524288;          // +2 MiB
    float* hst = chV + 524288;          // +2 MiB
    float* scC = hst + 524288;          // +2 MiB
    float* scV = scC + 32768;           // +128 KiB
    float* sst = scV + 32768;           // +128 KiB

    transpose4<<<1024, 256, 0, stream>>>(Wz, Wh, W1, W2, Wzt, Wht, W1t, W2t);
    // a = bf16(LN1(x))
    ln_k<<<8192, 256, 0, stream>>>(x, ln1g, ln1b, a, 32768);
    // kb = a @ Wz + bz ; hp = a @ Wh + bh  (bf16, dual-B single pass)
    gemm_bt<0><<<1024, 256, 0, stream>>>(a, Wzt, Wht, bz, bh, nullptr, kb, hp);
    scanA<<<2048, 256, 0, stream>>>(kb, hp, chC, chV);
    scanB1<<<128, 256, 0, stream>>>(chC, chV, scC, scV);
    scanB2<<<8, 256, 0, stream>>>(scC, scV, sst);
    scanB3<<<128, 256, 0, stream>>>(chC, chV, sst, hst);
    // d_out = x + h (fp32) ; kb <- bf16(LN2(d_out)) in-place
    scanC_ln<<<1024, 512, 0, stream>>>(kb, hp, hst, x, ln2g, ln2b, out, kb);
    // a = relu(kb @ W1 + b1)  (bf16 hidden; 'a' region now free)
    gemm_bt<1><<<1024, 256, 0, stream>>>(kb, W1t, nullptr, b1, nullptr, nullptr, a, nullptr);
    // d_out = a @ W2 + b2 + d_out  (fp32)
    gemm_bt<2><<<1024, 256, 0, stream>>>(a, W2t, nullptr, b2, nullptr, out, out, nullptr);
}

// Round 5
// 314.050 us; speedup vs baseline: 1.2641x; 1.2641x over previous
//
#include <hip/hip_runtime.h>

typedef unsigned short u16;
typedef unsigned int u32;
typedef __bf16 bf16x8 __attribute__((ext_vector_type(8)));
typedef float f32x4 __attribute__((ext_vector_type(4)));
typedef u16 u16x8 __attribute__((ext_vector_type(8)));

__device__ __forceinline__ u16 f2bf(float f) {
    union { float f; u32 i; } v; v.f = f;
    u32 x = v.i;
    u32 r = (x + 0x7fffu + ((x >> 16) & 1u)) >> 16;
    return (u16)r;
}
__device__ __forceinline__ float bf2f(u16 u) {
    union { u32 i; float f; } v; v.i = ((u32)u) << 16; return v.f;
}
__device__ __forceinline__ u16 f2h(float f) {
    union { _Float16 h; u16 u; } v; v.h = (_Float16)f; return v.u;
}
__device__ __forceinline__ float h2f(u16 u) {
    union { _Float16 h; u16 u; } v; v.u = u; return (float)v.h;
}

// async global->LDS, 16B per lane. LDS dest must be lane-linear per wave.
__device__ __forceinline__ void gld16(const void* g, void* l) {
    __builtin_amdgcn_global_load_lds(
        (const __attribute__((address_space(1))) void*)g,
        (__attribute__((address_space(3))) void*)l, 16, 0, 0);
}

// -------- weight transpose+convert: 4 matrices [512][512] fp32 -> bf16^T ---
__global__ __launch_bounds__(256) void transpose4(
    const float* __restrict__ s0, const float* __restrict__ s1,
    const float* __restrict__ s2, const float* __restrict__ s3,
    u16* __restrict__ d0, u16* __restrict__ d1,
    u16* __restrict__ d2, u16* __restrict__ d3)
{
    int bx = blockIdx.x;
    int mat = bx >> 8;          // 0..3
    int tile = bx & 255;        // 16x16 tiles of 32x32
    int tx = (tile & 15) * 32;
    int ty = (tile >> 4) * 32;
    const float* src = (mat == 0) ? s0 : (mat == 1) ? s1 : (mat == 2) ? s2 : s3;
    u16* dst = (mat == 0) ? d0 : (mat == 1) ? d1 : (mat == 2) ? d2 : d3;

    __shared__ u16 tl[32][33];
    int col = threadIdx.x & 31;
    int r8  = threadIdx.x >> 5;   // 0..7
    #pragma unroll
    for (int k = 0; k < 4; ++k) {
        int rr = r8 + k * 8;
        tl[rr][col] = f2bf(src[(ty + rr) * 512 + tx + col]);
    }
    __syncthreads();
    #pragma unroll
    for (int k = 0; k < 4; ++k) {
        int rr = r8 + k * 8;
        dst[(tx + rr) * 512 + ty + col] = tl[col][rr];
    }
}

// -------- LayerNorm over H=512: fp32 in -> bf16 out, one wave per row -----
__global__ __launch_bounds__(256) void ln_k(
    const float* __restrict__ x, const float* __restrict__ g,
    const float* __restrict__ b, u16* __restrict__ y, int rows)
{
    int gid = blockIdx.x * blockDim.x + threadIdx.x;
    int row = gid >> 6;
    int lane = gid & 63;
    if (row >= rows) return;

    const float* xr = x + (size_t)row * 512 + lane * 8;
    float4 a0 = *(const float4*)xr;
    float4 a1 = *(const float4*)(xr + 4);
    float f[8] = {a0.x, a0.y, a0.z, a0.w, a1.x, a1.y, a1.z, a1.w};
    float s = 0.f, s2 = 0.f;
    #pragma unroll
    for (int e = 0; e < 8; ++e) { s += f[e]; s2 += f[e] * f[e]; }
    #pragma unroll
    for (int o = 32; o > 0; o >>= 1) { s += __shfl_xor(s, o); s2 += __shfl_xor(s2, o); }
    const float inv = 1.0f / 512.0f;
    float mean = s * inv;
    float var  = s2 * inv - mean * mean;
    float rstd = rsqrtf(var + 1e-5f);

    float4 g0 = *(const float4*)(g + lane * 8);
    float4 g1 = *(const float4*)(g + lane * 8 + 4);
    float4 b0 = *(const float4*)(b + lane * 8);
    float4 b1 = *(const float4*)(b + lane * 8 + 4);
    float gg[8] = {g0.x, g0.y, g0.z, g0.w, g1.x, g1.y, g1.z, g1.w};
    float bb[8] = {b0.x, b0.y, b0.z, b0.w, b1.x, b1.y, b1.z, b1.w};
    u16x8 ov;
    #pragma unroll
    for (int e = 0; e < 8; ++e)
        ov[e] = f2bf((f[e] - mean) * rstd * gg[e] + bb[e]);
    *(u16x8*)(y + (size_t)row * 512 + lane * 8) = ov;
}

// -------- GEMM: C[M,N] = A[M,K](bf16) @ Bt[N,K](bf16)^T, 128x128 tile -----
// Staging via global_load_lds (width 16), granule-XOR on source + read side
// (round-1 verified: FETCH ideal, LDS conflicts 0, 62us).
// MODE 0 (minGRU gate pass): dual-B -> k = A@Bz + bz ; hp = A@Bh + bh, then
//   IN-EPILOGUE computes gates c = sigmoid(-k), v = sigmoid(k)*g(hp) in fp32
//   from the accumulators, stores them as fp16 (cb, vb) via an LDS stage
//   (coalesced 16B stores), AND folds the per-chunk (C,V) scan composition
//   (32 t-rows per chunk, 4 chunks per block) directly from LDS -> chC/chV.
//   This replaces the former scanA dispatch (64 MB re-read) entirely.
// MODE 1: out0 = relu(A@B0 + bias0) (bf16, scalar epilogue as round-1)
// MODE 2: out0 = A@B0 + bias0 + resid (fp32 out; same-thread alias-safe)
template <int MODE>
__global__ __launch_bounds__(256, 2) void gemm_bt(
    const u16* __restrict__ A, const u16* __restrict__ Bt0,
    const u16* __restrict__ Bt1, const float* __restrict__ bias0,
    const float* __restrict__ bias1, const float* __restrict__ resid,
    void* __restrict__ out0v, u16* __restrict__ out1,
    float* __restrict__ chCp, float* __restrict__ chVp)
{
    constexpr int Kd = 512, Nd = 512;
    // MODE0: staging 12288 u16 (24 KiB), epilogue 2 x [128][136] u16 fp16
    //        (union, disjoint lifetime) = 34816 u16 = 68 KiB -> 2 blocks/CU.
    constexpr int SMEM_N = (MODE == 0) ? 34816 : 8192;
    __shared__ __align__(16) u16 smem[SMEM_N];
    u16* As  = smem;
    u16* Bs0 = smem + 4096;
    u16* Bs1 = smem + 8192;   // used only when MODE==0

    // XCD-contiguous tile remap (1024 % 8 == 0 -> bijective)
    int bx = blockIdx.x;
    bx = (bx & 7) * 128 + (bx >> 3);
    int m0 = (bx >> 2) * 128;
    int n0 = (bx & 3) * 128;
    int tid = threadIdx.x;
    int lane = tid & 63;
    int w = tid >> 6;
    int wm = w & 1, wn = w >> 1;
    int l16 = lane & 15;
    int quad = lane >> 4;

    f32x4 acc0[4][4] = {};
    f32x4 acc1[4][4] = {};

    // staging: chunk ch covers LDS granule ch (16B); it carries global
    // granule (ch&3) ^ ((row>>1)&3) of row = ch>>2.
    int ch0 = tid, ch1 = tid + 256;
    int row0 = ch0 >> 2, row1 = ch1 >> 2;
    int g0 = (ch0 & 3) ^ ((ch0 >> 3) & 3);
    int g1 = (ch1 & 3) ^ ((ch1 >> 3) & 3);
    const u16* a0p  = A   + (size_t)(m0 + row0) * Kd + g0 * 8;
    const u16* a1p  = A   + (size_t)(m0 + row1) * Kd + g1 * 8;
    const u16* b00p = Bt0 + (size_t)(n0 + row0) * Kd + g0 * 8;
    const u16* b01p = Bt0 + (size_t)(n0 + row1) * Kd + g1 * 8;
    const u16* b10p = (MODE == 0) ? Bt1 + (size_t)(n0 + row0) * Kd + g0 * 8 : nullptr;
    const u16* b11p = (MODE == 0) ? Bt1 + (size_t)(n0 + row1) * Kd + g1 * 8 : nullptr;

    for (int kt = 0; kt < Kd / 32; ++kt) {
        int k0 = kt * 32;
        gld16(a0p  + k0, &As [ch0 * 8]);
        gld16(a1p  + k0, &As [ch1 * 8]);
        gld16(b00p + k0, &Bs0[ch0 * 8]);
        gld16(b01p + k0, &Bs0[ch1 * 8]);
        if (MODE == 0) {
            gld16(b10p + k0, &Bs1[ch0 * 8]);
            gld16(b11p + k0, &Bs1[ch1 * 8]);
        }
        __syncthreads();

        bf16x8 af[4], bf0[4], bf1[4];
        #pragma unroll
        for (int i = 0; i < 4; ++i) {
            int ra = wm * 64 + i * 16 + l16;
            int rb = wn * 64 + i * 16 + l16;
            int ga = quad ^ ((ra >> 1) & 3);
            int gb = quad ^ ((rb >> 1) & 3);
            af[i]  = *(const bf16x8*)&As [ra * 32 + ga * 8];
            bf0[i] = *(const bf16x8*)&Bs0[rb * 32 + gb * 8];
            if (MODE == 0)
                bf1[i] = *(const bf16x8*)&Bs1[rb * 32 + gb * 8];
        }
        #pragma unroll
        for (int i = 0; i < 4; ++i)
            #pragma unroll
            for (int j = 0; j < 4; ++j) {
                acc0[i][j] = __builtin_amdgcn_mfma_f32_16x16x32_bf16(af[i], bf0[j], acc0[i][j], 0, 0, 0);
                if (MODE == 0)
                    acc1[i][j] = __builtin_amdgcn_mfma_f32_16x16x32_bf16(af[i], bf1[j], acc1[i][j], 0, 0, 0);
            }
        __syncthreads();
    }
    // (final loop sync: all MFMA + LDS reads + DMA drained -> smem reusable)

    if (MODE == 0) {
        // ---- gate epilogue: fp32 gates from accumulators -> fp16 LDS ----
        u16* Cc = smem;            // [128][136] fp16 c
        u16* Cv = smem + 17408;    // [128][136] fp16 v   (128*136 = 17408)
        #pragma unroll
        for (int j = 0; j < 4; ++j) {
            int col = n0 + wn * 64 + j * 16 + l16;
            float bk = bias0[col];
            float bhv = bias1[col];
            #pragma unroll
            for (int i = 0; i < 4; ++i)
                #pragma unroll
                for (int r = 0; r < 4; ++r) {
                    int lr = wm * 64 + i * 16 + quad * 4 + r;
                    int lc = wn * 64 + j * 16 + l16;
                    float kk = acc0[i][j][r] + bk;
                    float hh = acc1[i][j][r] + bhv;
                    float z = 1.f / (1.f + __expf(-kk));   // sigmoid(k)
                    float c = 1.f / (1.f + __expf(kk));    // sigmoid(-k)
                    float gg = (hh >= 0.f) ? (hh + 0.5f) : 1.f / (1.f + __expf(-hh));
                    Cc[lr * 136 + lc] = f2h(c);
                    Cv[lr * 136 + lc] = f2h(z * gg);
                }
        }
        __syncthreads();
        // coalesced 16B/lane global stores of cb (out0v) and vb (out1)
        u16* cb = (u16*)out0v;
        #pragma unroll
        for (int k = 0; k < 8; ++k) {
            int c = tid + k * 256;
            int row = c >> 4, c8 = c & 15;
            size_t off = (size_t)(m0 + row) * Nd + n0 + c8 * 8;
            *(u16x8*)(cb   + off) = *(const u16x8*)&Cc[row * 136 + c8 * 8];
            *(u16x8*)(out1 + off) = *(const u16x8*)&Cv[row * 136 + c8 * 8];
        }
        // chunk-state fold (replaces scanA): 4 chunks x 128 h per block,
        // 512 units over 256 threads -> 2 per thread.
        int h2 = tid & 127;
        #pragma unroll
        for (int u = 0; u < 2; ++u) {
            int cc = (tid >> 7) + u * 2;     // 0..3
            float C = 1.f, V = 0.f;
            #pragma unroll 8
            for (int t = 0; t < 32; ++t) {
                int lr = cc * 32 + t;
                float c = h2f(Cc[lr * 136 + h2]);
                float v = h2f(Cv[lr * 136 + h2]);
                C *= c;
                V = fmaf(c, V, v);
            }
            int g_row = m0 + cc * 32;
            int b = g_row >> 13;             // 8192 rows per batch
            int chgl = (g_row & 8191) >> 5;  // 0..255
            int idx = chgl * 2048 + b * 512 + n0 + h2;
            chCp[idx] = C;
            chVp[idx] = V;
        }
    } else {
        // ---- round-1 scalar epilogues (proven) ----
        #pragma unroll
        for (int j = 0; j < 4; ++j) {
            int col = n0 + wn * 64 + j * 16 + l16;
            float b0 = bias0[col];
            #pragma unroll
            for (int i = 0; i < 4; ++i) {
                #pragma unroll
                for (int r = 0; r < 4; ++r) {
                    int row = m0 + wm * 64 + i * 16 + quad * 4 + r;
                    size_t off = (size_t)row * Nd + col;
                    float v0 = acc0[i][j][r] + b0;
                    if (MODE == 1) {
                        ((u16*)out0v)[off] = f2bf(fmaxf(v0, 0.f));
                    } else {
                        ((float*)out0v)[off] = v0 + resid[off];
                    }
                }
            }
        }
    }
}

// -------- minGRU scan: h_t = c_t*h_{t-1} + v_t, h_0 = 0.5 -----------------
// Gates (c,v fp16) are produced by gemm_bt<0>'s epilogue, which also emits
// per-chunk (C,V). 3-level chunk-state scan, chunk length 32.

// Pass B1: compose 16 chunks -> superchunk state (16 superchunks/seq).
__global__ __launch_bounds__(256) void scanB1(
    const float* __restrict__ chC, const float* __restrict__ chV,
    float* __restrict__ scC, float* __restrict__ scV)
{
    int gid = blockIdx.x * 256 + threadIdx.x;  // 32768 threads
    int s = gid & 2047;
    int sc = gid >> 11;    // 0..15
    float C = 1.f, V = 0.f;
    #pragma unroll 4
    for (int i = 0; i < 16; ++i) {
        int ch = sc * 16 + i;
        float c = chC[ch * 2048 + s];
        float v = chV[ch * 2048 + s];
        C *= c;
        V = fmaf(c, V, v);
    }
    scC[sc * 2048 + s] = C;
    scV[sc * 2048 + s] = V;
}

// Pass B2: serial scan over 16 superchunk states; write start h per sc.
__global__ __launch_bounds__(256) void scanB2(
    const float* __restrict__ scC, const float* __restrict__ scV,
    float* __restrict__ sst)
{
    int s = blockIdx.x * 256 + threadIdx.x;   // 0..2047
    float hcur = 0.5f;
    #pragma unroll
    for (int sc = 0; sc < 16; ++sc) {
        sst[sc * 2048 + s] = hcur;
        hcur = fmaf(scC[sc * 2048 + s], hcur, scV[sc * 2048 + s]);
    }
}

// Pass B3: replay 16 chunks inside each superchunk; write start h per chunk.
__global__ __launch_bounds__(256) void scanB3(
    const float* __restrict__ chC, const float* __restrict__ chV,
    const float* __restrict__ sst, float* __restrict__ hst)
{
    int gid = blockIdx.x * 256 + threadIdx.x;  // 32768 threads
    int s = gid & 2047;
    int sc = gid >> 11;
    float hcur = sst[sc * 2048 + s];
    #pragma unroll 4
    for (int i = 0; i < 16; ++i) {
        int ch = sc * 16 + i;
        hst[ch * 2048 + s] = hcur;
        hcur = fmaf(chC[ch * 2048 + s], hcur, chV[ch * 2048 + s]);
    }
}

// Pass C: replay chunk from fp16 gates; x2 = x + h (fp32 in, fp32 out).
// No transcendentals: serial chain is 32 fmaf only.
__global__ __launch_bounds__(256) void scanC(
    const u16* __restrict__ cb, const u16* __restrict__ vb,
    const float* __restrict__ hst, const float* __restrict__ x,
    float* __restrict__ x2)
{
    int gid = blockIdx.x * 256 + threadIdx.x;   // 524288 threads
    int h = gid & 511;
    int rest = gid >> 9;
    int b = rest & 3;
    int ch = rest >> 2;
    size_t base = ((size_t)(b * 8192 + ch * 32)) * 512 + h;
    float hcur = hst[ch * 2048 + b * 512 + h];
    #pragma unroll 8
    for (int t = 0; t < 32; ++t) {
        size_t off = base + (size_t)t * 512;
        float c = h2f(cb[off]);
        float v = h2f(vb[off]);
        hcur = fmaf(c, hcur, v);
        x2[off] = x[off] + hcur;
    }
}

// ---------------------------------------------------------------------------
// All I/O fp32 (per reference). Internals bf16 (GEMM) / fp16 (gates).
// ws layout (99.5 MiB, unchanged footprint):
//   wt  @ 0      : 2 MiB   (4 transposed bf16 weights)
//   a   @ 3.5 MiB: 32 MiB  bf16. Lifetimes: LN1-out (read by gemm0) ->
//     [hst @ a+0 (2M); scC/scV/sst @ a+2M (384K)] -> LN2-out (ln_k #2).
//   cb  @ 35.5 M : 32 MiB  fp16 c-gates -> (dead after scanC) FFN hidden.
//   vb  @ 67.5 M : 32 MiB  fp16 v-gates.
// chC/chV (2 MiB each) alias d_out (dead until scanC; consumed by scanB3
// before scanC overwrites d_out with x2).
// d_out holds x2 after scanC, then the final output (gemm2 reads resid[off]
// then writes out[off] from the same thread).
extern "C" void kernel_launch(void* const* d_in, const int* in_sizes, int n_in,
                              void* d_out, int out_size, void* d_ws, size_t ws_size,
                              hipStream_t stream)
{
    const float* x    = (const float*)d_in[0];
    const float* ln1g = (const float*)d_in[1];
    const float* ln1b = (const float*)d_in[2];
    const float* Wz   = (const float*)d_in[3];
    const float* bz   = (const float*)d_in[4];
    const float* Wh   = (const float*)d_in[5];
    const float* bh   = (const float*)d_in[6];
    const float* ln2g = (const float*)d_in[7];
    const float* ln2b = (const float*)d_in[8];
    const float* W1   = (const float*)d_in[9];
    const float* b1   = (const float*)d_in[10];
    const float* W2   = (const float*)d_in[11];
    const float* b2   = (const float*)d_in[12];
    float* out = (float*)d_out;

    char* ws = (char*)d_ws;
    constexpr size_t MB = 1024 * 1024;
    u16* Wzt = (u16*)(ws);
    u16* Wht = Wzt + 262144;
    u16* W1t = Wzt + 524288;
    u16* W2t = Wzt + 786432;
    u16* a  = (u16*)(ws + 3 * MB + 512 * 1024);   // LN1 out / LN2 out
    u16* cb = (u16*)(ws + 35 * MB + 512 * 1024);  // c gates / FFN hidden
    u16* vb = (u16*)(ws + 67 * MB + 512 * 1024);  // v gates
    // scan temps: hst & sc* alias 'a' (dead there); chC/chV alias d_out.
    float* hst = (float*)(ws + 3 * MB + 512 * 1024);
    float* scC = hst + 524288;          // +2 MiB
    float* scV = scC + 32768;           // +128 KiB
    float* sst = scV + 32768;           // +128 KiB
    float* chC = (float*)d_out;
    float* chV = chC + 524288;          // +2 MiB

    transpose4<<<1024, 256, 0, stream>>>(Wz, Wh, W1, W2, Wzt, Wht, W1t, W2t);
    // a = bf16(LN1(x))
    ln_k<<<8192, 256, 0, stream>>>(x, ln1g, ln1b, a, 32768);
    // cb,vb = fp16 gates of (a@Wz+bz, a@Wh+bh); chC/chV = per-chunk scan states
    gemm_bt<0><<<1024, 256, 0, stream>>>(a, Wzt, Wht, bz, bh, nullptr, cb, vb, chC, chV);
    scanB1<<<128, 256, 0, stream>>>(chC, chV, scC, scV);
    scanB2<<<8, 256, 0, stream>>>(scC, scV, sst);
    scanB3<<<128, 256, 0, stream>>>(chC, chV, sst, hst);
    // d_out = x + h  (fp32 residual stream; overwrites chC/chV - consumed)
    scanC<<<2048, 256, 0, stream>>>(cb, vb, hst, x, out);
    // a = bf16(LN2(d_out))  (hst region dead)
    ln_k<<<8192, 256, 0, stream>>>(out, ln2g, ln2b, a, 32768);
    // cb = relu(a @ W1 + b1)  (bf16 hidden; gate buffers dead)
    gemm_bt<1><<<1024, 256, 0, stream>>>(a, W1t, nullptr, b1, nullptr, nullptr, cb, nullptr, nullptr, nullptr);
    // d_out = cb @ W2 + b2 + d_out  (fp32)
    gemm_bt<2><<<1024, 256, 0, stream>>>(cb, W2t, nullptr, b2, nullptr, out, out, nullptr, nullptr, nullptr);
}

// Round 6
// 303.976 us; speedup vs baseline: 1.3060x; 1.0331x over previous
//
#include <hip/hip_runtime.h>

typedef unsigned short u16;
typedef unsigned int u32;
typedef __bf16 bf16x8 __attribute__((ext_vector_type(8)));
typedef float f32x4 __attribute__((ext_vector_type(4)));
typedef u16 u16x8 __attribute__((ext_vector_type(8)));

__device__ __forceinline__ u16 f2bf(float f) {
    union { float f; u32 i; } v; v.f = f;
    u32 x = v.i;
    u32 r = (x + 0x7fffu + ((x >> 16) & 1u)) >> 16;
    return (u16)r;
}
__device__ __forceinline__ float bf2f(u16 u) {
    union { u32 i; float f; } v; v.i = ((u32)u) << 16; return v.f;
}
__device__ __forceinline__ u16 f2h(float f) {
    union { _Float16 h; u16 u; } v; v.h = (_Float16)f; return v.u;
}
__device__ __forceinline__ float h2f(u16 u) {
    union { _Float16 h; u16 u; } v; v.u = u; return (float)v.h;
}

// async global->LDS, 16B per lane. LDS dest must be lane-linear per wave.
__device__ __forceinline__ void gld16(const void* g, void* l) {
    __builtin_amdgcn_global_load_lds(
        (const __attribute__((address_space(1))) void*)g,
        (__attribute__((address_space(3))) void*)l, 16, 0, 0);
}

// -------- weight transpose+convert: 4 matrices [512][512] fp32 -> bf16^T ---
__global__ __launch_bounds__(256) void transpose4(
    const float* __restrict__ s0, const float* __restrict__ s1,
    const float* __restrict__ s2, const float* __restrict__ s3,
    u16* __restrict__ d0, u16* __restrict__ d1,
    u16* __restrict__ d2, u16* __restrict__ d3)
{
    int bx = blockIdx.x;
    int mat = bx >> 8;          // 0..3
    int tile = bx & 255;        // 16x16 tiles of 32x32
    int tx = (tile & 15) * 32;
    int ty = (tile >> 4) * 32;
    const float* src = (mat == 0) ? s0 : (mat == 1) ? s1 : (mat == 2) ? s2 : s3;
    u16* dst = (mat == 0) ? d0 : (mat == 1) ? d1 : (mat == 2) ? d2 : d3;

    __shared__ u16 tl[32][33];
    int col = threadIdx.x & 31;
    int r8  = threadIdx.x >> 5;   // 0..7
    #pragma unroll
    for (int k = 0; k < 4; ++k) {
        int rr = r8 + k * 8;
        tl[rr][col] = f2bf(src[(ty + rr) * 512 + tx + col]);
    }
    __syncthreads();
    #pragma unroll
    for (int k = 0; k < 4; ++k) {
        int rr = r8 + k * 8;
        dst[(tx + rr) * 512 + ty + col] = tl[col][rr];
    }
}

// -------- LayerNorm over H=512: fp32 in -> bf16 out, one wave per row -----
__global__ __launch_bounds__(256) void ln_k(
    const float* __restrict__ x, const float* __restrict__ g,
    const float* __restrict__ b, u16* __restrict__ y, int rows)
{
    int gid = blockIdx.x * blockDim.x + threadIdx.x;
    int row = gid >> 6;
    int lane = gid & 63;
    if (row >= rows) return;

    const float* xr = x + (size_t)row * 512 + lane * 8;
    float4 a0 = *(const float4*)xr;
    float4 a1 = *(const float4*)(xr + 4);
    float f[8] = {a0.x, a0.y, a0.z, a0.w, a1.x, a1.y, a1.z, a1.w};
    float s = 0.f, s2 = 0.f;
    #pragma unroll
    for (int e = 0; e < 8; ++e) { s += f[e]; s2 += f[e] * f[e]; }
    #pragma unroll
    for (int o = 32; o > 0; o >>= 1) { s += __shfl_xor(s, o); s2 += __shfl_xor(s2, o); }
    const float inv = 1.0f / 512.0f;
    float mean = s * inv;
    float var  = s2 * inv - mean * mean;
    float rstd = rsqrtf(var + 1e-5f);

    float4 g0 = *(const float4*)(g + lane * 8);
    float4 g1 = *(const float4*)(g + lane * 8 + 4);
    float4 b0 = *(const float4*)(b + lane * 8);
    float4 b1 = *(const float4*)(b + lane * 8 + 4);
    float gg[8] = {g0.x, g0.y, g0.z, g0.w, g1.x, g1.y, g1.z, g1.w};
    float bb[8] = {b0.x, b0.y, b0.z, b0.w, b1.x, b1.y, b1.z, b1.w};
    u16x8 ov;
    #pragma unroll
    for (int e = 0; e < 8; ++e)
        ov[e] = f2bf((f[e] - mean) * rstd * gg[e] + bb[e]);
    *(u16x8*)(y + (size_t)row * 512 + lane * 8) = ov;
}

// -------- GEMM: C[M,N] = A[M,K](bf16) @ Bt[N,K](bf16)^T, 128x128 tile -----
// Staging via global_load_lds (width 16), granule-XOR on source + read side
// (round-1 verified: FETCH ideal, LDS conflicts 0, 62us).
// MODE 0 (minGRU gate pass): dual-B -> k = A@Bz + bz ; hp = A@Bh + bh.
//   Epilogue computes gates c = sigmoid(-k), v = sigmoid(k)*g(hp) in fp32
//   using HW rcp (__builtin_amdgcn_rcpf) + the identity sigmoid(-k) =
//   1 - sigmoid(k)  (no IEEE divide sequences!), stores them fp16 with
//   the proven round-1 scalar store pattern, and folds the per-chunk
//   (C,V) scan composition IN REGISTERS: per thread two 4-row segments
//   per chunk, ordered cross-quad __shfl_xor combine (compose is
//   associative, not commutative -> order by quad bit), then S_hi∘S_lo.
//   Replaces the former scanA dispatch with zero LDS/barrier overhead.
// MODE 1: out0 = relu(A@B0 + bias0) (bf16, scalar epilogue as round-1)
// MODE 2: out0 = A@B0 + bias0 + resid (fp32 out; same-thread alias-safe)
template <int MODE>
__global__ __launch_bounds__(256, 2) void gemm_bt(
    const u16* __restrict__ A, const u16* __restrict__ Bt0,
    const u16* __restrict__ Bt1, const float* __restrict__ bias0,
    const float* __restrict__ bias1, const float* __restrict__ resid,
    void* __restrict__ out0v, u16* __restrict__ out1,
    float* __restrict__ chCp, float* __restrict__ chVp)
{
    constexpr int Kd = 512, Nd = 512;
    constexpr int SMEM_N = (MODE == 0) ? 12288 : 8192;
    __shared__ __align__(16) u16 smem[SMEM_N];
    u16* As  = smem;
    u16* Bs0 = smem + 4096;
    u16* Bs1 = smem + 8192;   // used only when MODE==0

    // XCD-contiguous tile remap (1024 % 8 == 0 -> bijective)
    int bx = blockIdx.x;
    bx = (bx & 7) * 128 + (bx >> 3);
    int m0 = (bx >> 2) * 128;
    int n0 = (bx & 3) * 128;
    int tid = threadIdx.x;
    int lane = tid & 63;
    int w = tid >> 6;
    int wm = w & 1, wn = w >> 1;
    int l16 = lane & 15;
    int quad = lane >> 4;

    f32x4 acc0[4][4] = {};
    f32x4 acc1[4][4] = {};

    // staging: chunk ch covers LDS granule ch (16B); it carries global
    // granule (ch&3) ^ ((row>>1)&3) of row = ch>>2.
    int ch0 = tid, ch1 = tid + 256;
    int row0 = ch0 >> 2, row1 = ch1 >> 2;
    int g0 = (ch0 & 3) ^ ((ch0 >> 3) & 3);
    int g1 = (ch1 & 3) ^ ((ch1 >> 3) & 3);
    const u16* a0p  = A   + (size_t)(m0 + row0) * Kd + g0 * 8;
    const u16* a1p  = A   + (size_t)(m0 + row1) * Kd + g1 * 8;
    const u16* b00p = Bt0 + (size_t)(n0 + row0) * Kd + g0 * 8;
    const u16* b01p = Bt0 + (size_t)(n0 + row1) * Kd + g1 * 8;
    const u16* b10p = (MODE == 0) ? Bt1 + (size_t)(n0 + row0) * Kd + g0 * 8 : nullptr;
    const u16* b11p = (MODE == 0) ? Bt1 + (size_t)(n0 + row1) * Kd + g1 * 8 : nullptr;

    for (int kt = 0; kt < Kd / 32; ++kt) {
        int k0 = kt * 32;
        gld16(a0p  + k0, &As [ch0 * 8]);
        gld16(a1p  + k0, &As [ch1 * 8]);
        gld16(b00p + k0, &Bs0[ch0 * 8]);
        gld16(b01p + k0, &Bs0[ch1 * 8]);
        if (MODE == 0) {
            gld16(b10p + k0, &Bs1[ch0 * 8]);
            gld16(b11p + k0, &Bs1[ch1 * 8]);
        }
        __syncthreads();

        bf16x8 af[4], bf0[4], bf1[4];
        #pragma unroll
        for (int i = 0; i < 4; ++i) {
            int ra = wm * 64 + i * 16 + l16;
            int rb = wn * 64 + i * 16 + l16;
            int ga = quad ^ ((ra >> 1) & 3);
            int gb = quad ^ ((rb >> 1) & 3);
            af[i]  = *(const bf16x8*)&As [ra * 32 + ga * 8];
            bf0[i] = *(const bf16x8*)&Bs0[rb * 32 + gb * 8];
            if (MODE == 0)
                bf1[i] = *(const bf16x8*)&Bs1[rb * 32 + gb * 8];
        }
        #pragma unroll
        for (int i = 0; i < 4; ++i)
            #pragma unroll
            for (int j = 0; j < 4; ++j) {
                acc0[i][j] = __builtin_amdgcn_mfma_f32_16x16x32_bf16(af[i], bf0[j], acc0[i][j], 0, 0, 0);
                if (MODE == 0)
                    acc1[i][j] = __builtin_amdgcn_mfma_f32_16x16x32_bf16(af[i], bf1[j], acc1[i][j], 0, 0, 0);
            }
        __syncthreads();
    }

    if (MODE == 0) {
        // ---- gate epilogue, all in registers ----
        u16* cb = (u16*)out0v;
        #pragma unroll
        for (int p = 0; p < 2; ++p) {
            // chunk p of this thread's 64-row half: rows m0+wm*64+p*32 ..+31
            int grow = m0 + wm * 64 + p * 32;
            int bb_  = grow >> 13;              // batch (8192 rows each)
            int chgl = (grow & 8191) >> 5;      // global chunk 0..255
            #pragma unroll
            for (int j = 0; j < 4; ++j) {
                int col = n0 + wn * 64 + j * 16 + l16;
                float bk  = bias0[col];
                float bh2 = bias1[col];
                float Cs[2], Vs[2];
                #pragma unroll
                for (int ii = 0; ii < 2; ++ii) {
                    int i = 2 * p + ii;
                    float C = 1.f, V = 0.f;
                    #pragma unroll
                    for (int r = 0; r < 4; ++r) {
                        int row = m0 + wm * 64 + i * 16 + quad * 4 + r;
                        float kk = acc0[i][j][r] + bk;
                        float hh = acc1[i][j][r] + bh2;
                        // z = sigmoid(k); c = sigmoid(-k) = 1-z (exact id.)
                        float z = __builtin_amdgcn_rcpf(1.f + __expf(-kk));
                        float c = 1.f - z;
                        float gs = __builtin_amdgcn_rcpf(1.f + __expf(-hh));
                        float gg = (hh >= 0.f) ? (hh + 0.5f) : gs;
                        float v = z * gg;
                        size_t off = (size_t)row * Nd + col;
                        cb[off]   = f2h(c);
                        out1[off] = f2h(v);
                        C *= c;                 // append element t
                        V = fmaf(c, V, v);
                    }
                    Cs[ii] = C; Vs[ii] = V;
                }
                // ordered cross-quad combine per 16-row sub-block.
                // combine(later U, earlier L): C = CL*CU ; V = CU*VL + VU
                #pragma unroll
                for (int ii = 0; ii < 2; ++ii) {
                    float C = Cs[ii], V = Vs[ii];
                    float oc = __shfl_xor(C, 16), ov = __shfl_xor(V, 16);
                    V = (quad & 1) ? fmaf(C, ov, V) : fmaf(oc, V, ov);
                    C *= oc;
                    oc = __shfl_xor(C, 32); ov = __shfl_xor(V, 32);
                    V = (quad & 2) ? fmaf(C, ov, V) : fmaf(oc, V, ov);
                    C *= oc;
                    Cs[ii] = C; Vs[ii] = V;
                }
                // chunk (32 rows) = S_hi ∘ S_lo
                float Cch = Cs[0] * Cs[1];
                float Vch = fmaf(Cs[1], Vs[0], Vs[1]);
                if (quad == 0) {
                    int idx = chgl * 2048 + bb_ * 512 + col;
                    chCp[idx] = Cch;
                    chVp[idx] = Vch;
                }
            }
        }
    } else {
        // ---- round-1 scalar epilogues (proven) ----
        #pragma unroll
        for (int j = 0; j < 4; ++j) {
            int col = n0 + wn * 64 + j * 16 + l16;
            float b0 = bias0[col];
            #pragma unroll
            for (int i = 0; i < 4; ++i) {
                #pragma unroll
                for (int r = 0; r < 4; ++r) {
                    int row = m0 + wm * 64 + i * 16 + quad * 4 + r;
                    size_t off = (size_t)row * Nd + col;
                    float v0 = acc0[i][j][r] + b0;
                    if (MODE == 1) {
                        ((u16*)out0v)[off] = f2bf(fmaxf(v0, 0.f));
                    } else {
                        ((float*)out0v)[off] = v0 + resid[off];
                    }
                }
            }
        }
    }
}

// -------- minGRU scan: h_t = c_t*h_{t-1} + v_t, h_0 = 0.5 -----------------
// Gates (c,v fp16) and per-chunk (C,V) are produced by gemm_bt<0>'s
// epilogue. 3-level chunk-state scan, chunk length 32.

// Pass B1: compose 16 chunks -> superchunk state (16 superchunks/seq).
__global__ __launch_bounds__(256) void scanB1(
    const float* __restrict__ chC, const float* __restrict__ chV,
    float* __restrict__ scC, float* __restrict__ scV)
{
    int gid = blockIdx.x * 256 + threadIdx.x;  // 32768 threads
    int s = gid & 2047;
    int sc = gid >> 11;    // 0..15
    float C = 1.f, V = 0.f;
    #pragma unroll 4
    for (int i = 0; i < 16; ++i) {
        int ch = sc * 16 + i;
        float c = chC[ch * 2048 + s];
        float v = chV[ch * 2048 + s];
        C *= c;
        V = fmaf(c, V, v);
    }
    scC[sc * 2048 + s] = C;
    scV[sc * 2048 + s] = V;
}

// Pass B2: serial scan over 16 superchunk states; write start h per sc.
__global__ __launch_bounds__(256) void scanB2(
    const float* __restrict__ scC, const float* __restrict__ scV,
    float* __restrict__ sst)
{
    int s = blockIdx.x * 256 + threadIdx.x;   // 0..2047
    float hcur = 0.5f;
    #pragma unroll
    for (int sc = 0; sc < 16; ++sc) {
        sst[sc * 2048 + s] = hcur;
        hcur = fmaf(scC[sc * 2048 + s], hcur, scV[sc * 2048 + s]);
    }
}

// Pass B3: replay 16 chunks inside each superchunk; write start h per chunk.
__global__ __launch_bounds__(256) void scanB3(
    const float* __restrict__ chC, const float* __restrict__ chV,
    const float* __restrict__ sst, float* __restrict__ hst)
{
    int gid = blockIdx.x * 256 + threadIdx.x;  // 32768 threads
    int s = gid & 2047;
    int sc = gid >> 11;
    float hcur = sst[sc * 2048 + s];
    #pragma unroll 4
    for (int i = 0; i < 16; ++i) {
        int ch = sc * 16 + i;
        hst[ch * 2048 + s] = hcur;
        hcur = fmaf(chC[ch * 2048 + s], hcur, chV[ch * 2048 + s]);
    }
}

// Pass C: replay chunk from fp16 gates; x2 = x + h (fp32 in, fp32 out).
// No transcendentals: serial chain is 32 fmaf only.
__global__ __launch_bounds__(256) void scanC(
    const u16* __restrict__ cb, const u16* __restrict__ vb,
    const float* __restrict__ hst, const float* __restrict__ x,
    float* __restrict__ x2)
{
    int gid = blockIdx.x * 256 + threadIdx.x;   // 524288 threads
    int h = gid & 511;
    int rest = gid >> 9;
    int b = rest & 3;
    int ch = rest >> 2;
    size_t base = ((size_t)(b * 8192 + ch * 32)) * 512 + h;
    float hcur = hst[ch * 2048 + b * 512 + h];
    #pragma unroll 8
    for (int t = 0; t < 32; ++t) {
        size_t off = base + (size_t)t * 512;
        float c = h2f(cb[off]);
        float v = h2f(vb[off]);
        hcur = fmaf(c, hcur, v);
        x2[off] = x[off] + hcur;
    }
}

// ---------------------------------------------------------------------------
// All I/O fp32 (per reference). Internals bf16 (GEMM) / fp16 (gates).
// ws layout (99.5 MiB, unchanged footprint):
//   wt  @ 0      : 2 MiB   (4 transposed bf16 weights)
//   a   @ 3.5 MiB: 32 MiB  bf16. Lifetimes: LN1-out (read by gemm0) ->
//     [hst @ a+0 (2M); scC/scV/sst @ a+2M (384K)] -> LN2-out (ln_k #2).
//   cb  @ 35.5 M : 32 MiB  fp16 c-gates -> (dead after scanC) FFN hidden.
//   vb  @ 67.5 M : 32 MiB  fp16 v-gates.
// chC/chV (2 MiB each) alias d_out (dead until scanC; consumed by scanB3
// before scanC overwrites d_out with x2).
// d_out holds x2 after scanC, then the final output (gemm2 reads resid[off]
// then writes out[off] from the same thread).
extern "C" void kernel_launch(void* const* d_in, const int* in_sizes, int n_in,
                              void* d_out, int out_size, void* d_ws, size_t ws_size,
                              hipStream_t stream)
{
    const float* x    = (const float*)d_in[0];
    const float* ln1g = (const float*)d_in[1];
    const float* ln1b = (const float*)d_in[2];
    const float* Wz   = (const float*)d_in[3];
    const float* bz   = (const float*)d_in[4];
    const float* Wh   = (const float*)d_in[5];
    const float* bh   = (const float*)d_in[6];
    const float* ln2g = (const float*)d_in[7];
    const float* ln2b = (const float*)d_in[8];
    const float* W1   = (const float*)d_in[9];
    const float* b1   = (const float*)d_in[10];
    const float* W2   = (const float*)d_in[11];
    const float* b2   = (const float*)d_in[12];
    float* out = (float*)d_out;

    char* ws = (char*)d_ws;
    constexpr size_t MB = 1024 * 1024;
    u16* Wzt = (u16*)(ws);
    u16* Wht = Wzt + 262144;
    u16* W1t = Wzt + 524288;
    u16* W2t = Wzt + 786432;
    u16* a  = (u16*)(ws + 3 * MB + 512 * 1024);   // LN1 out / LN2 out
    u16* cb = (u16*)(ws + 35 * MB + 512 * 1024);  // c gates / FFN hidden
    u16* vb = (u16*)(ws + 67 * MB + 512 * 1024);  // v gates
    // scan temps: hst & sc* alias 'a' (dead there); chC/chV alias d_out.
    float* hst = (float*)(ws + 3 * MB + 512 * 1024);
    float* scC = hst + 524288;          // +2 MiB
    float* scV = scC + 32768;           // +128 KiB
    float* sst = scV + 32768;           // +128 KiB
    float* chC = (float*)d_out;
    float* chV = chC + 524288;          // +2 MiB

    transpose4<<<1024, 256, 0, stream>>>(Wz, Wh, W1, W2, Wzt, Wht, W1t, W2t);
    // a = bf16(LN1(x))
    ln_k<<<8192, 256, 0, stream>>>(x, ln1g, ln1b, a, 32768);
    // cb,vb = fp16 gates of (a@Wz+bz, a@Wh+bh); chC/chV = per-chunk states
    gemm_bt<0><<<1024, 256, 0, stream>>>(a, Wzt, Wht, bz, bh, nullptr, cb, vb, chC, chV);
    scanB1<<<128, 256, 0, stream>>>(chC, chV, scC, scV);
    scanB2<<<8, 256, 0, stream>>>(scC, scV, sst);
    scanB3<<<128, 256, 0, stream>>>(chC, chV, sst, hst);
    // d_out = x + h  (fp32 residual stream; overwrites chC/chV - consumed)
    scanC<<<2048, 256, 0, stream>>>(cb, vb, hst, x, out);
    // a = bf16(LN2(d_out))  (hst region dead)
    ln_k<<<8192, 256, 0, stream>>>(out, ln2g, ln2b, a, 32768);
    // cb = relu(a @ W1 + b1)  (bf16 hidden; gate buffers dead)
    gemm_bt<1><<<1024, 256, 0, stream>>>(a, W1t, nullptr, b1, nullptr, nullptr, cb, nullptr, nullptr, nullptr);
    // d_out = cb @ W2 + b2 + d_out  (fp32)
    gemm_bt<2><<<1024, 256, 0, stream>>>(cb, W2t, nullptr, b2, nullptr, out, out, nullptr, nullptr, nullptr);
}

// Round 7
// 296.156 us; speedup vs baseline: 1.3405x; 1.0264x over previous
//
#include <hip/hip_runtime.h>

typedef unsigned short u16;
typedef unsigned int u32;
typedef __bf16 bf16x8 __attribute__((ext_vector_type(8)));
typedef float f32x4 __attribute__((ext_vector_type(4)));
typedef u16 u16x8 __attribute__((ext_vector_type(8)));

__device__ __forceinline__ u16 f2bf(float f) {
    union { float f; u32 i; } v; v.f = f;
    u32 x = v.i;
    u32 r = (x + 0x7fffu + ((x >> 16) & 1u)) >> 16;
    return (u16)r;
}
__device__ __forceinline__ float bf2f(u16 u) {
    union { u32 i; float f; } v; v.i = ((u32)u) << 16; return v.f;
}
__device__ __forceinline__ u16 f2h(float f) {
    union { _Float16 h; u16 u; } v; v.h = (_Float16)f; return v.u;
}
__device__ __forceinline__ float h2f(u16 u) {
    union { _Float16 h; u16 u; } v; v.u = u; return (float)v.h;
}

// async global->LDS, 16B per lane. LDS dest must be lane-linear per wave.
__device__ __forceinline__ void gld16(const void* g, void* l) {
    __builtin_amdgcn_global_load_lds(
        (const __attribute__((address_space(1))) void*)g,
        (__attribute__((address_space(3))) void*)l, 16, 0, 0);
}

// -------- weight transpose+convert: 4 matrices [512][512] fp32 -> bf16^T ---
__global__ __launch_bounds__(256) void transpose4(
    const float* __restrict__ s0, const float* __restrict__ s1,
    const float* __restrict__ s2, const float* __restrict__ s3,
    u16* __restrict__ d0, u16* __restrict__ d1,
    u16* __restrict__ d2, u16* __restrict__ d3)
{
    int bx = blockIdx.x;
    int mat = bx >> 8;          // 0..3
    int tile = bx & 255;        // 16x16 tiles of 32x32
    int tx = (tile & 15) * 32;
    int ty = (tile >> 4) * 32;
    const float* src = (mat == 0) ? s0 : (mat == 1) ? s1 : (mat == 2) ? s2 : s3;
    u16* dst = (mat == 0) ? d0 : (mat == 1) ? d1 : (mat == 2) ? d2 : d3;

    __shared__ u16 tl[32][33];
    int col = threadIdx.x & 31;
    int r8  = threadIdx.x >> 5;   // 0..7
    #pragma unroll
    for (int k = 0; k < 4; ++k) {
        int rr = r8 + k * 8;
        tl[rr][col] = f2bf(src[(ty + rr) * 512 + tx + col]);
    }
    __syncthreads();
    #pragma unroll
    for (int k = 0; k < 4; ++k) {
        int rr = r8 + k * 8;
        dst[(tx + rr) * 512 + ty + col] = tl[col][rr];
    }
}

// -------- LayerNorm over H=512: fp32 in -> bf16 out, one wave per row -----
__global__ __launch_bounds__(256) void ln_k(
    const float* __restrict__ x, const float* __restrict__ g,
    const float* __restrict__ b, u16* __restrict__ y, int rows)
{
    int gid = blockIdx.x * blockDim.x + threadIdx.x;
    int row = gid >> 6;
    int lane = gid & 63;
    if (row >= rows) return;

    const float* xr = x + (size_t)row * 512 + lane * 8;
    float4 a0 = *(const float4*)xr;
    float4 a1 = *(const float4*)(xr + 4);
    float f[8] = {a0.x, a0.y, a0.z, a0.w, a1.x, a1.y, a1.z, a1.w};
    float s = 0.f, s2 = 0.f;
    #pragma unroll
    for (int e = 0; e < 8; ++e) { s += f[e]; s2 += f[e] * f[e]; }
    #pragma unroll
    for (int o = 32; o > 0; o >>= 1) { s += __shfl_xor(s, o); s2 += __shfl_xor(s2, o); }
    const float inv = 1.0f / 512.0f;
    float mean = s * inv;
    float var  = s2 * inv - mean * mean;
    float rstd = rsqrtf(var + 1e-5f);

    float4 g0 = *(const float4*)(g + lane * 8);
    float4 g1 = *(const float4*)(g + lane * 8 + 4);
    float4 b0 = *(const float4*)(b + lane * 8);
    float4 b1 = *(const float4*)(b + lane * 8 + 4);
    float gg[8] = {g0.x, g0.y, g0.z, g0.w, g1.x, g1.y, g1.z, g1.w};
    float bb[8] = {b0.x, b0.y, b0.z, b0.w, b1.x, b1.y, b1.z, b1.w};
    u16x8 ov;
    #pragma unroll
    for (int e = 0; e < 8; ++e)
        ov[e] = f2bf((f[e] - mean) * rstd * gg[e] + bb[e]);
    *(u16x8*)(y + (size_t)row * 512 + lane * 8) = ov;
}

// -------- GEMM: C[M,N] = A[M,K](bf16) @ Bt[N,K](bf16)^T, 128x128 tile -----
// Double-buffered prefetch K-loop (catalog T3 "minimum 2-phase"): stage
// tile kt+1 BEFORE computing tile kt; single __syncthreads per K-step
// (its vmcnt(0)+lgkmcnt(0) drain covers the prefetch RAW and read WAR).
// Staging via global_load_lds (16B), granule-XOR source+read (verified:
// FETCH ideal, 0 conflicts).
// MODE 0 (minGRU gate pass): dual-B -> k = A@Bz+bz ; hp = A@Bh+bh.
//   Epilogue computes c = sigmoid(-k) = 1-z, v = z*g(hp) with HW rcp,
//   packs (c,v) fp16 into ONE u32 store per element, and folds per-chunk
//   (C,V) in registers (ordered cross-quad shfl combine) -> chC/chV.
// MODE 1: out0 = relu(A@B0 + bias0) (bf16)
// MODE 2: out0 = A@B0 + bias0 + resid (fp32; same-thread alias-safe)
template <int MODE>
__global__ __launch_bounds__(256, 2) void gemm_bt(
    const u16* __restrict__ A, const u16* __restrict__ Bt0,
    const u16* __restrict__ Bt1, const float* __restrict__ bias0,
    const float* __restrict__ bias1, const float* __restrict__ resid,
    void* __restrict__ out0v,
    float* __restrict__ chCp, float* __restrict__ chVp)
{
    constexpr int Kd = 512, Nd = 512;
    constexpr int BUF = (MODE == 0) ? 12288 : 8192;   // u16 per LDS buffer
    __shared__ __align__(16) u16 smem[2 * BUF];       // MODE0 48K else 32K

    // XCD-contiguous tile remap (1024 % 8 == 0 -> bijective)
    int bx = blockIdx.x;
    bx = (bx & 7) * 128 + (bx >> 3);
    int m0 = (bx >> 2) * 128;
    int n0 = (bx & 3) * 128;
    int tid = threadIdx.x;
    int lane = tid & 63;
    int w = tid >> 6;
    int wm = w & 1, wn = w >> 1;
    int l16 = lane & 15;
    int quad = lane >> 4;

    f32x4 acc0[4][4] = {};
    f32x4 acc1[4][4] = {};

    // staging: chunk ch covers LDS granule ch (16B); it carries global
    // granule (ch&3) ^ ((row>>1)&3) of row = ch>>2.
    int ch0 = tid, ch1 = tid + 256;
    int row0 = ch0 >> 2, row1 = ch1 >> 2;
    int g0 = (ch0 & 3) ^ ((ch0 >> 3) & 3);
    int g1 = (ch1 & 3) ^ ((ch1 >> 3) & 3);
    const u16* a0p  = A   + (size_t)(m0 + row0) * Kd + g0 * 8;
    const u16* a1p  = A   + (size_t)(m0 + row1) * Kd + g1 * 8;
    const u16* b00p = Bt0 + (size_t)(n0 + row0) * Kd + g0 * 8;
    const u16* b01p = Bt0 + (size_t)(n0 + row1) * Kd + g1 * 8;
    const u16* b10p = (MODE == 0) ? Bt1 + (size_t)(n0 + row0) * Kd + g0 * 8 : nullptr;
    const u16* b11p = (MODE == 0) ? Bt1 + (size_t)(n0 + row1) * Kd + g1 * 8 : nullptr;

#define STAGE(sl, kt) { \
    int k0_ = (kt) * 32; \
    u16* As_ = smem + (sl) * BUF; \
    gld16(a0p  + k0_, &As_[ch0 * 8]); \
    gld16(a1p  + k0_, &As_[ch1 * 8]); \
    gld16(b00p + k0_, &As_[4096 + ch0 * 8]); \
    gld16(b01p + k0_, &As_[4096 + ch1 * 8]); \
    if (MODE == 0) { \
        gld16(b10p + k0_, &As_[8192 + ch0 * 8]); \
        gld16(b11p + k0_, &As_[8192 + ch1 * 8]); \
    } }

    STAGE(0, 0);
    __syncthreads();                 // tile 0 landed

    for (int kt = 0; kt < Kd / 32; ++kt) {
        int cur = kt & 1;
        if (kt < Kd / 32 - 1) STAGE(cur ^ 1, kt + 1);   // prefetch next

        const u16* As  = smem + cur * BUF;
        const u16* Bs0 = As + 4096;
        const u16* Bs1 = As + 8192;
        bf16x8 af[4], bf0[4], bf1[4];
        #pragma unroll
        for (int i = 0; i < 4; ++i) {
            int ra = wm * 64 + i * 16 + l16;
            int rb = wn * 64 + i * 16 + l16;
            int ga = quad ^ ((ra >> 1) & 3);
            int gb = quad ^ ((rb >> 1) & 3);
            af[i]  = *(const bf16x8*)&As [ra * 32 + ga * 8];
            bf0[i] = *(const bf16x8*)&Bs0[rb * 32 + gb * 8];
            if (MODE == 0)
                bf1[i] = *(const bf16x8*)&Bs1[rb * 32 + gb * 8];
        }
        #pragma unroll
        for (int i = 0; i < 4; ++i)
            #pragma unroll
            for (int j = 0; j < 4; ++j) {
                acc0[i][j] = __builtin_amdgcn_mfma_f32_16x16x32_bf16(af[i], bf0[j], acc0[i][j], 0, 0, 0);
                if (MODE == 0)
                    acc1[i][j] = __builtin_amdgcn_mfma_f32_16x16x32_bf16(af[i], bf1[j], acc1[i][j], 0, 0, 0);
            }
        // single barrier per K-step: drains prefetch DMA (vmcnt) and
        // publishes that all waves finished reading buf[cur] (WAR for
        // the next iteration's stage into buf[cur]).
        __syncthreads();
    }
#undef STAGE

    if (MODE == 0) {
        // ---- gate epilogue, all in registers; one u32 store/element ----
        u32* cvb = (u32*)out0v;
        #pragma unroll
        for (int p = 0; p < 2; ++p) {
            // chunk p of this thread's 64-row half: rows m0+wm*64+p*32 ..+31
            int grow = m0 + wm * 64 + p * 32;
            int bb_  = grow >> 13;              // batch (8192 rows each)
            int chgl = (grow & 8191) >> 5;      // global chunk 0..255
            #pragma unroll
            for (int j = 0; j < 4; ++j) {
                int col = n0 + wn * 64 + j * 16 + l16;
                float bk  = bias0[col];
                float bh2 = bias1[col];
                float Cs[2], Vs[2];
                #pragma unroll
                for (int ii = 0; ii < 2; ++ii) {
                    int i = 2 * p + ii;
                    float C = 1.f, V = 0.f;
                    #pragma unroll
                    for (int r = 0; r < 4; ++r) {
                        int row = m0 + wm * 64 + i * 16 + quad * 4 + r;
                        float kk = acc0[i][j][r] + bk;
                        float hh = acc1[i][j][r] + bh2;
                        // z = sigmoid(k); c = sigmoid(-k) = 1-z (exact id.)
                        float z = __builtin_amdgcn_rcpf(1.f + __expf(-kk));
                        float c = 1.f - z;
                        float gs = __builtin_amdgcn_rcpf(1.f + __expf(-hh));
                        float gg = (hh >= 0.f) ? (hh + 0.5f) : gs;
                        float v = z * gg;
                        cvb[(size_t)row * Nd + col] =
                            (u32)f2h(c) | ((u32)f2h(v) << 16);
                        C *= c;                 // append element t
                        V = fmaf(c, V, v);
                    }
                    Cs[ii] = C; Vs[ii] = V;
                }
                // ordered cross-quad combine per 16-row sub-block.
                // combine(later U, earlier L): C = CL*CU ; V = CU*VL + VU
                #pragma unroll
                for (int ii = 0; ii < 2; ++ii) {
                    float C = Cs[ii], V = Vs[ii];
                    float oc = __shfl_xor(C, 16), ov = __shfl_xor(V, 16);
                    V = (quad & 1) ? fmaf(C, ov, V) : fmaf(oc, V, ov);
                    C *= oc;
                    oc = __shfl_xor(C, 32); ov = __shfl_xor(V, 32);
                    V = (quad & 2) ? fmaf(C, ov, V) : fmaf(oc, V, ov);
                    C *= oc;
                    Cs[ii] = C; Vs[ii] = V;
                }
                // chunk (32 rows) = S_hi ∘ S_lo
                float Cch = Cs[0] * Cs[1];
                float Vch = fmaf(Cs[1], Vs[0], Vs[1]);
                if (quad == 0) {
                    int idx = chgl * 2048 + bb_ * 512 + col;
                    chCp[idx] = Cch;
                    chVp[idx] = Vch;
                }
            }
        }
    } else {
        // ---- proven scalar epilogues ----
        #pragma unroll
        for (int j = 0; j < 4; ++j) {
            int col = n0 + wn * 64 + j * 16 + l16;
            float b0 = bias0[col];
            #pragma unroll
            for (int i = 0; i < 4; ++i) {
                #pragma unroll
                for (int r = 0; r < 4; ++r) {
                    int row = m0 + wm * 64 + i * 16 + quad * 4 + r;
                    size_t off = (size_t)row * Nd + col;
                    float v0 = acc0[i][j][r] + b0;
                    if (MODE == 1) {
                        ((u16*)out0v)[off] = f2bf(fmaxf(v0, 0.f));
                    } else {
                        ((float*)out0v)[off] = v0 + resid[off];
                    }
                }
            }
        }
    }
}

// -------- minGRU scan: h_t = c_t*h_{t-1} + v_t, h_0 = 0.5 -----------------
// Gates (c,v fp16 packed u32) and per-chunk (C,V) come from gemm_bt<0>.
// 3-level chunk-state scan, chunk length 32.

// Pass B1: compose 16 chunks -> superchunk state (16 superchunks/seq).
__global__ __launch_bounds__(256) void scanB1(
    const float* __restrict__ chC, const float* __restrict__ chV,
    float* __restrict__ scC, float* __restrict__ scV)
{
    int gid = blockIdx.x * 256 + threadIdx.x;  // 32768 threads
    int s = gid & 2047;
    int sc = gid >> 11;    // 0..15
    float C = 1.f, V = 0.f;
    #pragma unroll 4
    for (int i = 0; i < 16; ++i) {
        int ch = sc * 16 + i;
        float c = chC[ch * 2048 + s];
        float v = chV[ch * 2048 + s];
        C *= c;
        V = fmaf(c, V, v);
    }
    scC[sc * 2048 + s] = C;
    scV[sc * 2048 + s] = V;
}

// Pass B2: serial scan over 16 superchunk states; write start h per sc.
__global__ __launch_bounds__(256) void scanB2(
    const float* __restrict__ scC, const float* __restrict__ scV,
    float* __restrict__ sst)
{
    int s = blockIdx.x * 256 + threadIdx.x;   // 0..2047
    float hcur = 0.5f;
    #pragma unroll
    for (int sc = 0; sc < 16; ++sc) {
        sst[sc * 2048 + s] = hcur;
        hcur = fmaf(scC[sc * 2048 + s], hcur, scV[sc * 2048 + s]);
    }
}

// Pass B3: replay 16 chunks inside each superchunk; write start h per chunk.
__global__ __launch_bounds__(256) void scanB3(
    const float* __restrict__ chC, const float* __restrict__ chV,
    const float* __restrict__ sst, float* __restrict__ hst)
{
    int gid = blockIdx.x * 256 + threadIdx.x;  // 32768 threads
    int s = gid & 2047;
    int sc = gid >> 11;
    float hcur = sst[sc * 2048 + s];
    #pragma unroll 4
    for (int i = 0; i < 16; ++i) {
        int ch = sc * 16 + i;
        hst[ch * 2048 + s] = hcur;
        hcur = fmaf(chC[ch * 2048 + s], hcur, chV[ch * 2048 + s]);
    }
}

// Pass C: replay chunk from packed fp16 gates; x2 = x + h.
// 2 adjacent h per thread: one 8B uint2 gate load + float2 x/out per step.
__global__ __launch_bounds__(256) void scanC(
    const u32* __restrict__ cv, const float* __restrict__ hst,
    const float* __restrict__ x, float* __restrict__ x2)
{
    int gid = blockIdx.x * 256 + threadIdx.x;   // 262144 threads
    int h2 = (gid & 255) * 2;
    int rest = gid >> 8;
    int b = rest & 3;
    int ch = rest >> 2;                          // 0..255
    size_t base = ((size_t)(b * 8192 + ch * 32)) * 512 + h2;
    int sidx = ch * 2048 + b * 512 + h2;
    float h0 = hst[sidx], h1 = hst[sidx + 1];
    #pragma unroll 8
    for (int t = 0; t < 32; ++t) {
        size_t off = base + (size_t)t * 512;
        uint2 g2 = *(const uint2*)(cv + off);
        float2 xx = *(const float2*)(x + off);
        h0 = fmaf(h2f((u16)(g2.x & 0xffffu)), h0, h2f((u16)(g2.x >> 16)));
        h1 = fmaf(h2f((u16)(g2.y & 0xffffu)), h1, h2f((u16)(g2.y >> 16)));
        float2 o; o.x = xx.x + h0; o.y = xx.y + h1;
        *(float2*)(x2 + off) = o;
    }
}

// ---------------------------------------------------------------------------
// All I/O fp32 (per reference). Internals bf16 (GEMM) / fp16 (gates).
// ws layout (99.5 MiB, unchanged footprint):
//   wt  @ 0      : 2 MiB   (4 transposed bf16 weights)
//   a   @ 3.5 MiB: 32 MiB  bf16. Lifetimes: LN1-out (read by gemm0) ->
//     [hst @ a+0 (2M); scC/scV/sst @ a+2M (384K)] -> LN2-out (ln_k #2).
//   cv  @ 35.5 M : 64 MiB  u32 packed (c,v) gates -> first 32 MiB reused
//     as FFN hidden after scanC.
// chC/chV (2 MiB each) alias d_out (dead until scanC; consumed by scanB3
// before scanC overwrites d_out with x2).
// d_out holds x2 after scanC, then the final output (gemm2 reads resid[off]
// then writes out[off] from the same thread).
extern "C" void kernel_launch(void* const* d_in, const int* in_sizes, int n_in,
                              void* d_out, int out_size, void* d_ws, size_t ws_size,
                              hipStream_t stream)
{
    const float* x    = (const float*)d_in[0];
    const float* ln1g = (const float*)d_in[1];
    const float* ln1b = (const float*)d_in[2];
    const float* Wz   = (const float*)d_in[3];
    const float* bz   = (const float*)d_in[4];
    const float* Wh   = (const float*)d_in[5];
    const float* bh   = (const float*)d_in[6];
    const float* ln2g = (const float*)d_in[7];
    const float* ln2b = (const float*)d_in[8];
    const float* W1   = (const float*)d_in[9];
    const float* b1   = (const float*)d_in[10];
    const float* W2   = (const float*)d_in[11];
    const float* b2   = (const float*)d_in[12];
    float* out = (float*)d_out;

    char* ws = (char*)d_ws;
    constexpr size_t MB = 1024 * 1024;
    u16* Wzt = (u16*)(ws);
    u16* Wht = Wzt + 262144;
    u16* W1t = Wzt + 524288;
    u16* W2t = Wzt + 786432;
    u16* a   = (u16*)(ws + 3 * MB + 512 * 1024);   // LN1 out / LN2 out
    u32* cv  = (u32*)(ws + 35 * MB + 512 * 1024);  // packed gates (64 MiB)
    u16* hid = (u16*)(ws + 35 * MB + 512 * 1024);  // FFN hidden (reuses cv)
    // scan temps: hst & sc* alias 'a' (dead there); chC/chV alias d_out.
    float* hst = (float*)(ws + 3 * MB + 512 * 1024);
    float* scC = hst + 524288;          // +2 MiB
    float* scV = scC + 32768;           // +128 KiB
    float* sst = scV + 32768;           // +128 KiB
    float* chC = (float*)d_out;
    float* chV = chC + 524288;          // +2 MiB

    transpose4<<<1024, 256, 0, stream>>>(Wz, Wh, W1, W2, Wzt, Wht, W1t, W2t);
    // a = bf16(LN1(x))
    ln_k<<<8192, 256, 0, stream>>>(x, ln1g, ln1b, a, 32768);
    // cv = packed fp16 gates of (a@Wz+bz, a@Wh+bh); chC/chV = chunk states
    gemm_bt<0><<<1024, 256, 0, stream>>>(a, Wzt, Wht, bz, bh, nullptr, cv, chC, chV);
    scanB1<<<128, 256, 0, stream>>>(chC, chV, scC, scV);
    scanB2<<<8, 256, 0, stream>>>(scC, scV, sst);
    scanB3<<<128, 256, 0, stream>>>(chC, chV, sst, hst);
    // d_out = x + h  (fp32 residual stream; overwrites chC/chV - consumed)
    scanC<<<1024, 256, 0, stream>>>(cv, hst, x, out);
    // a = bf16(LN2(d_out))  (hst region dead)
    ln_k<<<8192, 256, 0, stream>>>(out, ln2g, ln2b, a, 32768);
    // hid = relu(a @ W1 + b1)  (bf16; cv region dead)
    gemm_bt<1><<<1024, 256, 0, stream>>>(a, W1t, nullptr, b1, nullptr, nullptr, hid, nullptr, nullptr);
    // d_out = hid @ W2 + b2 + d_out  (fp32)
    gemm_bt<2><<<1024, 256, 0, stream>>>(hid, W2t, nullptr, b2, nullptr, out, out, nullptr, nullptr);
}